// Round 7
// baseline (103.665 us; speedup 1.0000x reference)
//
#include <hip/hip_runtime.h>

#define L    2048
#define HALF 1024
#define NM   10
#define NG   20
#define NF   30

#define NBC2 2000   // k_coarse blocks (one best per block)
#define NBF2 1125   // k_fine blocks

// fws layout (floats): td[HALF], then float4 tab[NM*HALF] = {log2|cos|, log2|sin|, sin(phi), 0}
#define OFF_TD  0
#define OFF_TAB HALF
#define FWS_FLOATS (OFF_TAB + 4*NM*HALF)   // 41984 floats

// ---- VALU-only transcendentals (no v_exp/v_log: those are ~60 cyc/wave64) ----
__device__ __forceinline__ float fast_exp2(float x) {
  float n = __builtin_rintf(x);
  float f = x - n;                       // f in [-0.5, 0.5]
  float p = 1.535336188319500e-4f;       // Cephes exp2f minimax, rel err ~2e-8
  p = fmaf(p, f, 1.339887440266574e-3f);
  p = fmaf(p, f, 9.618437357674640e-3f);
  p = fmaf(p, f, 5.550332471162809e-2f);
  p = fmaf(p, f, 2.402264791363012e-1f);
  p = fmaf(p, f, 6.931472028550421e-1f);
  p = fmaf(p, f, 1.0f);
  return __builtin_ldexpf(p, (int)n);    // v_ldexp_f32 handles full exp range
}

__device__ __forceinline__ float fast_log2(float u) {
  float m = __builtin_amdgcn_frexp_mant(u);      // [0.5, 1)
  int e = __builtin_amdgcn_frexp_exp(u);
  float ef = (float)e;
  bool c = m < 0.70710678f;
  m = c ? m + m : m;                             // -> [sqrt(0.5), sqrt(2))
  ef = c ? ef - 1.0f : ef;
  float x = m - 1.0f;                            // [-0.2929, 0.4142]
  float z = x * x;
  float p = 7.0376836292e-2f;                    // Cephes logf poly
  p = fmaf(p, x, -1.1514610310e-1f);
  p = fmaf(p, x,  1.1676998740e-1f);
  p = fmaf(p, x, -1.2420140846e-1f);
  p = fmaf(p, x,  1.4249322787e-1f);
  p = fmaf(p, x, -1.6668057665e-1f);
  p = fmaf(p, x,  2.0000714765e-1f);
  p = fmaf(p, x, -2.4999993993e-1f);
  p = fmaf(p, x,  3.3333331174e-1f);
  float y = (x * z) * p;
  y = fmaf(-0.5f, z, y);
  return fmaf(x + y, 1.44269504088896341f, ef);  // ln -> log2, + exponent
}

__device__ __forceinline__ float grid20(int i) {
  // jnp.logspace(-1,1,20)[i] = 10^(-1 + 2i/19)
  double e = -1.0 + 2.0 * (double)i / 19.0;
  return (float)exp2(e * 3.3219280948873623478703194294894);
}

__device__ __forceinline__ float finev(float c, int j) {
  // jnp.linspace(0.8c, 1.2c, 30)[j]
  return (float)((double)c * 0.8 + (double)j * ((double)c * 0.4 / 29.0));
}

// mse from pair-sums: sg == 0 exactly (antisymmetry), S = 2*sgg_pairs
__device__ __forceinline__ double mse_from(double sgg2, double sgt, double sum_tt) {
  double S = sgg2; if (S < 0.0) S = 0.0;
  double d = sqrt(S / (double)(L - 1)) + 1e-6;
  return (S / (d * d) - 2.0 * sgt / d + sum_tt) / (double)L;
}

// (v,t) wave reduction + block merge (all lanes valid)
__device__ __forceinline__ void vt_wave_reduce(double& v, int& t) {
  for (int o = 32; o > 0; o >>= 1) {
    double ov = __shfl_down(v, o);
    int ot = __shfl_down(t, o);
    if (ov < v || (ov == v && ot < t)) { v = ov; t = ot; }
  }
}

__device__ __forceinline__ void vt_block_merge(double& v, int& t,
                                               double* sv, int* st) {
  int lane = threadIdx.x & 63, w = threadIdx.x >> 6;
  vt_wave_reduce(v, t);
  if (lane == 0) { sv[w] = v; st[w] = t; }
  __syncthreads();
  if (threadIdx.x == 0) {
    for (int k = 1; k < 4; k++)
      if (sv[k] < v || (sv[k] == v && st[k] < t)) { v = sv[k]; t = st[k]; }
  }
}

// ---------------- K1: setup (block 0) + tables (blocks 1..40) --------------
__global__ __launch_bounds__(256) void k_init(const float* __restrict__ x,
                                              const int* __restrict__ freqp,
                                              float* __restrict__ fws,
                                              double* __restrict__ dws) {
  if (blockIdx.x == 0) {
    int tid = threadIdx.x;
    int lane = tid & 63, w = tid >> 6;
    __shared__ double sh[8];
    __shared__ double s_mean, s_d;

    double sx = 0.0, sxx = 0.0;
    for (int l = tid; l < L; l += 256) {
      double v = (double)x[l];
      sx += v; sxx += v * v;
    }
    for (int o = 32; o > 0; o >>= 1) { sx += __shfl_down(sx, o); sxx += __shfl_down(sxx, o); }
    if (lane == 0) { sh[w] = sx; sh[4 + w] = sxx; }
    __syncthreads();
    if (tid == 0) {
      sx = sh[0] + sh[1] + sh[2] + sh[3];
      sxx = sh[4] + sh[5] + sh[6] + sh[7];
      double mean = sx / (double)L;
      double S = sxx - sx * sx / (double)L; if (S < 0.0) S = 0.0;
      double sd = sqrt(S / (double)(L - 1));
      s_mean = mean; s_d = sd + 1e-6;
    }
    __syncthreads();
    double mean = s_mean, d = s_d;

    double stt = 0.0;
    for (int l = tid; l < HALF; l += 256) {
      float tva = (float)(((double)x[l] - mean) / d);
      float tvb = (float)(((double)x[L - 1 - l] - mean) / d);
      fws[OFF_TD + l] = tva - tvb;
      stt += (double)tva * (double)tva + (double)tvb * (double)tvb;
    }
    for (int o = 32; o > 0; o >>= 1) { stt += __shfl_down(stt, o); }
    __syncthreads();
    if (lane == 0) { sh[w] = stt; }
    __syncthreads();
    if (tid == 0) { dws[1] = sh[0] + sh[1] + sh[2] + sh[3]; }
  } else {
    int idx = (blockIdx.x - 1) * 256 + threadIdx.x;   // [0, NM*HALF)
    if (idx < NM * HALF) {
      int m = idx / HALF, l = idx % HALF;
      double freq = (double)freqp[0];
      double t = -1.0 + 2.0 * (double)l / 2047.0;
      double phi = 6.2831853071795864769 * freq * t;
      double ang = (double)(m + 1) * phi * 0.25;
      double sv, cv;
      sincos(ang, &sv, &cv);
      float4 v;
      v.x = (float)fmax(log2(fabs(cv)), -1.0e4);   // clamp: poly exp2 can't take -inf
      v.y = (float)fmax(log2(fabs(sv)), -1.0e4);
      v.z = (float)sin(phi);
      v.w = 0.0f;
      reinterpret_cast<float4*>(fws + OFF_TAB)[m * HALF + l] = v;
    }
  }
}

// ---------------- K2: coarse scan, fused finalize + block argmin -----------
// wave = (combo, i1ch): combo=(m,i2,i3) in [0,4000); i1ch in {0,1} (10 i1).
// 1024 pairs per wave (full range) -> lane0 holds final sums.
__global__ __launch_bounds__(256, 4) void k_coarse(const float* __restrict__ fws,
                                                   const double* __restrict__ dws,
                                                   double* __restrict__ bv,
                                                   int* __restrict__ bt) {
  int tid = threadIdx.x;
  int gwid = (blockIdx.x * 256 + tid) >> 6;   // [0, 8000)
  int lane = tid & 63, w = tid >> 6;
  int combo = gwid >> 1, i1ch = gwid & 1;
  int m = combo / (NG * NG);
  int i23 = combo % (NG * NG);
  float n2 = grid20(i23 / NG), n3 = grid20(i23 % NG);

  float r[10];
#pragma unroll
  for (int q = 0; q < 10; q++) r[q] = -1.0f / grid20(i1ch * 10 + q);

  const float4* tab = reinterpret_cast<const float4*>(fws + OFF_TAB) + m * HALF;
  const float* td = fws + OFF_TD;

  float sgg[10], sgt[10];
#pragma unroll
  for (int q = 0; q < 10; q++) { sgg[q] = 0.0f; sgt[q] = 0.0f; }

  for (int it = 0; it < 16; ++it) {
    int l = lane + it * 64;
    float4 tb = tab[l];
    float tdv = td[l];
    float lsum = fast_log2(fast_exp2(n2 * tb.x) + fast_exp2(n3 * tb.y));
    float spv = tb.z;
#pragma unroll
    for (int q = 0; q < 10; q++) {
      float g = fast_exp2(r[q] * lsum) * spv;
      sgg[q] = fmaf(g, g, sgg[q]);
      sgt[q] = fmaf(g, tdv, sgt[q]);
    }
  }

#pragma unroll
  for (int q = 0; q < 10; q++) {
    for (int o = 32; o > 0; o >>= 1) {
      sgg[q] += __shfl_down(sgg[q], o);
      sgt[q] += __shfl_down(sgt[q], o);
    }
  }

  __shared__ double sv[4];
  __shared__ int st[4];
  if (lane == 0) {
    double sum_tt = dws[1];
    double best = 1e300; int bts = 0x7fffffff;
    // t = (m*NG + i1)*400 + i23 ; q ascending => t ascending
#pragma unroll
    for (int q = 0; q < 10; q++) {
      double mse = mse_from(2.0 * (double)sgg[q], (double)sgt[q], sum_tt);
      if (mse < best) { best = mse; bts = (m * NG + i1ch * 10 + q) * (NG * NG) + i23; }
    }
    sv[w] = best; st[w] = bts;
  }
  __syncthreads();
  if (tid == 0) {
    double best = sv[0]; int bts = st[0];
    for (int k = 1; k < 4; k++)
      if (sv[k] < best || (sv[k] == best && st[k] < bts)) { best = sv[k]; bts = st[k]; }
    bv[blockIdx.x] = best; bt[blockIdx.x] = bts;
  }
}

// ---------------- K3: fine scan (in-block coarse argmin), fused finalize ---
// wave = (fc=(j2,j3), j1ch in {0..4}); 6 j1 x {sgg,sgt}; 1024 pairs per wave
__global__ __launch_bounds__(256, 4) void k_fine(const float* __restrict__ fws,
                                                 const double* __restrict__ dws,
                                                 const double* __restrict__ bvc,
                                                 const int* __restrict__ btc,
                                                 double* __restrict__ bvf,
                                                 int* __restrict__ btf) {
  __shared__ double sv[4];
  __shared__ int st[4];
  __shared__ int s_ci;
  {
    double v = 1e300; int t = 0x7fffffff;
    for (int i = threadIdx.x; i < NBC2; i += 256) {
      double ov = bvc[i]; int ot = btc[i];
      if (ov < v || (ov == v && ot < t)) { v = ov; t = ot; }
    }
    vt_block_merge(v, t, sv, st);
    if (threadIdx.x == 0) s_ci = t;
  }
  __syncthreads();
  int ci = s_ci;
  int m  = ci / (NG * NG * NG);
  int rr = ci % (NG * NG * NG);
  float cn1 = grid20(rr / (NG * NG));
  float cn2 = grid20((rr / NG) % NG);
  float cn3 = grid20(rr % NG);

  int tid = threadIdx.x;
  int gwid = (blockIdx.x * 256 + tid) >> 6;   // [0, 4500)
  int lane = tid & 63, w = tid >> 6;
  int fc = gwid / 5;
  int j1ch = gwid % 5;
  int j2 = fc / NF, j3 = fc % NF;
  float n2 = finev(cn2, j2), n3 = finev(cn3, j3);

  float r[6];
#pragma unroll
  for (int q = 0; q < 6; q++) r[q] = -1.0f / finev(cn1, j1ch * 6 + q);

  const float4* tab = reinterpret_cast<const float4*>(fws + OFF_TAB) + m * HALF;
  const float* td = fws + OFF_TD;

  float sgg[6], sgt[6];
#pragma unroll
  for (int q = 0; q < 6; q++) { sgg[q] = 0.0f; sgt[q] = 0.0f; }

  for (int it = 0; it < 16; ++it) {
    int l = lane + it * 64;
    float4 tb = tab[l];
    float tdv = td[l];
    float lsum = fast_log2(fast_exp2(n2 * tb.x) + fast_exp2(n3 * tb.y));
    float spv = tb.z;
#pragma unroll
    for (int q = 0; q < 6; q++) {
      float g = fast_exp2(r[q] * lsum) * spv;
      sgg[q] = fmaf(g, g, sgg[q]);
      sgt[q] = fmaf(g, tdv, sgt[q]);
    }
  }

#pragma unroll
  for (int q = 0; q < 6; q++) {
    for (int o = 32; o > 0; o >>= 1) {
      sgg[q] += __shfl_down(sgg[q], o);
      sgt[q] += __shfl_down(sgt[q], o);
    }
  }

  __syncthreads();   // reuse sv/st
  if (lane == 0) {
    double sum_tt = dws[1];
    double best = 1e300; int bts = 0x7fffffff;
    // t_fine = j1*NF*NF + fc ; q ascending => t ascending
#pragma unroll
    for (int q = 0; q < 6; q++) {
      double mse = mse_from(2.0 * (double)sgg[q], (double)sgt[q], sum_tt);
      if (mse < best) { best = mse; bts = (j1ch * 6 + q) * (NF * NF) + fc; }
    }
    sv[w] = best; st[w] = bts;
  }
  __syncthreads();
  if (tid == 0) {
    double best = sv[0]; int bts = st[0];
    for (int k = 1; k < 4; k++)
      if (sv[k] < best || (sv[k] == best && st[k] < bts)) { best = sv[k]; bts = st[k]; }
    bvf[blockIdx.x] = best; btf[blockIdx.x] = bts;
  }
}

// ---------------- K4: final argmins + emit ---------------------------------
__global__ __launch_bounds__(256) void k_out(const double* __restrict__ bvc,
                                             const int* __restrict__ btc,
                                             const double* __restrict__ bvf,
                                             const int* __restrict__ btf,
                                             float* __restrict__ out) {
  __shared__ double sv[4];
  __shared__ int st[4];
  __shared__ int s_ci;

  {
    double v = 1e300; int t = 0x7fffffff;
    for (int i = threadIdx.x; i < NBC2; i += 256) {
      double ov = bvc[i]; int ot = btc[i];
      if (ov < v || (ov == v && ot < t)) { v = ov; t = ot; }
    }
    vt_block_merge(v, t, sv, st);
    if (threadIdx.x == 0) s_ci = t;
  }
  __syncthreads();
  {
    double v = 1e300; int t = 0x7fffffff;
    for (int i = threadIdx.x; i < NBF2; i += 256) {
      double ov = bvf[i]; int ot = btf[i];
      if (ov < v || (ov == v && ot < t)) { v = ov; t = ot; }
    }
    vt_block_merge(v, t, sv, st);
    if (threadIdx.x == 0) {
      int ci = s_ci;
      int m  = ci / (NG * NG * NG);
      int rr = ci % (NG * NG * NG);
      float cn1 = grid20(rr / (NG * NG));
      float cn2 = grid20((rr / NG) % NG);
      float cn3 = grid20(rr % NG);
      int fi = t;
      int f1 = fi / (NF * NF), f2 = (fi / NF) % NF, f3 = fi % NF;
      out[0] = (float)(m + 1);
      out[1] = finev(cn1, f1);
      out[2] = finev(cn2, f2);
      out[3] = finev(cn3, f3);
    }
  }
}

extern "C" void kernel_launch(void* const* d_in, const int* in_sizes, int n_in,
                              void* d_out, int out_size, void* d_ws, size_t ws_size,
                              hipStream_t stream) {
  const float* x = (const float*)d_in[0];
  const int* freqp = (const int*)d_in[1];
  float* out = (float*)d_out;

  float* fws = (float*)d_ws;
  double* dws = (double*)(fws + FWS_FLOATS);   // byte offset 167936, 8-aligned
  double* bvc = dws + 2;                       // 2000 doubles
  double* bvf = bvc + NBC2;                    // 1125 doubles
  int* btc = (int*)(bvf + NBF2);               // 2000 ints
  int* btf = btc + NBC2;                       // 1125 ints

  hipLaunchKernelGGL(k_init,   dim3(1 + (NM * HALF + 255) / 256), dim3(256), 0, stream,
                     x, freqp, fws, dws);
  hipLaunchKernelGGL(k_coarse, dim3(NBC2), dim3(256), 0, stream, fws, dws, bvc, btc);
  hipLaunchKernelGGL(k_fine,   dim3(NBF2), dim3(256), 0, stream, fws, dws, bvc, btc, bvf, btf);
  hipLaunchKernelGGL(k_out,    dim3(1),    dim3(256), 0, stream, bvc, btc, bvf, btf, out);
}

// Round 8
// 82.759 us; speedup vs baseline: 1.2526x; 1.2526x over previous
//
#include <hip/hip_runtime.h>

#define L    2048
#define HALF 1024
#define NM   10
#define NG   20
#define NF   30

// ---- float workspace layout (indices in floats) ----
#define OFF_TD   0                       // td[1024]
#define OFF_SC   1024                    // float2 sc[1024] = {sin^2, sin*td}   (2048 floats)
#define OFF_TAB  3072                    // float4 tab[NM*HALF] = {lc, ls, sp, 0}  (40960 floats)
#define OFF_G20  44032                   // grid20 values [20]
#define OFF_R20  44052                   // -1/grid20 [20]
#define OFF_N1F  44072                   // fine n1 values [30]
#define OFF_N2F  44102
#define OFF_N3F  44132
#define OFF_RF   44162                   // -1/n1f [30]
#define OFF_CTAB 44192                   // lsum coarse [4000*1024]
#define OFF_FTAB (OFF_CTAB + 4000*1024)  // lsum fine [900*1024]
#define OFF_DWS  (OFF_FTAB + 900*1024)   // doubles region (byte ofs %8==0)

#define NCC  4000    // coarse combos (m,i2,i3); one block each
#define NFB  1125    // fine blocks (4 waves each, 4500 wave-jobs)

#define EXP2F(x) __builtin_amdgcn_exp2f(x)
#define LOG2F(x) __builtin_amdgcn_logf(x)

__device__ __forceinline__ float grid20(int i) {
  double e = -1.0 + 2.0 * (double)i / 19.0;
  return (float)exp2(e * 3.3219280948873623478703194294894);
}
__device__ __forceinline__ float finev(float c, int j) {
  return (float)((double)c * 0.8 + (double)j * ((double)c * 0.4 / 29.0));
}
__device__ __forceinline__ double mse_from(double sgg2, double sgt, double sum_tt) {
  double S = sgg2; if (S < 0.0) S = 0.0;
  double d = sqrt(S / (double)(L - 1)) + 1e-6;
  return (S / (d * d) - 2.0 * sgt / d + sum_tt) / (double)L;
}
__device__ __forceinline__ void vt_wave_reduce(double& v, int& t) {
  for (int o = 32; o > 0; o >>= 1) {
    double ov = __shfl_down(v, o);
    int ot = __shfl_down(t, o);
    if (ov < v || (ov == v && ot < t)) { v = ov; t = ot; }
  }
}
__device__ __forceinline__ void vt_block_merge(double& v, int& t, double* sv, int* st) {
  int lane = threadIdx.x & 63, w = threadIdx.x >> 6;
  vt_wave_reduce(v, t);
  if (lane == 0) { sv[w] = v; st[w] = t; }
  __syncthreads();
  if (threadIdx.x == 0) {
    for (int k = 1; k < 4; k++)
      if (sv[k] < v || (sv[k] == v && st[k] < t)) { v = sv[k]; t = st[k]; }
  }
}

// ---------------- K1: setup + trig tables + grid constants -----------------
__global__ __launch_bounds__(256) void k_init(const float* __restrict__ x,
                                              const int* __restrict__ freqp,
                                              float* __restrict__ fws,
                                              double* __restrict__ dstt) {
  if (blockIdx.x == 0) {
    int tid = threadIdx.x;
    int lane = tid & 63, w = tid >> 6;
    __shared__ double sh[8];
    __shared__ double s_mean, s_d;

    double sx = 0.0, sxx = 0.0;
    for (int l = tid; l < L; l += 256) {
      double v = (double)x[l];
      sx += v; sxx += v * v;
    }
    for (int o = 32; o > 0; o >>= 1) { sx += __shfl_down(sx, o); sxx += __shfl_down(sxx, o); }
    if (lane == 0) { sh[w] = sx; sh[4 + w] = sxx; }
    __syncthreads();
    if (tid == 0) {
      sx = sh[0] + sh[1] + sh[2] + sh[3];
      sxx = sh[4] + sh[5] + sh[6] + sh[7];
      double mean = sx / (double)L;
      double S = sxx - sx * sx / (double)L; if (S < 0.0) S = 0.0;
      s_mean = mean; s_d = sqrt(S / (double)(L - 1)) + 1e-6;
    }
    __syncthreads();
    double mean = s_mean, d = s_d;
    double freq = (double)freqp[0];

    double stt = 0.0;
    for (int l = tid; l < HALF; l += 256) {
      float tva = (float)(((double)x[l] - mean) / d);
      float tvb = (float)(((double)x[L - 1 - l] - mean) / d);
      float tdv = tva - tvb;
      fws[OFF_TD + l] = tdv;
      double t = -1.0 + 2.0 * (double)l / 2047.0;
      float spv = (float)sin(6.2831853071795864769 * freq * t);
      float2 scv; scv.x = spv * spv; scv.y = spv * tdv;
      reinterpret_cast<float2*>(fws + OFF_SC)[l] = scv;
      stt += (double)tva * (double)tva + (double)tvb * (double)tvb;
    }
    for (int o = 32; o > 0; o >>= 1) { stt += __shfl_down(stt, o); }
    __syncthreads();
    if (lane == 0) { sh[w] = stt; }
    __syncthreads();
    if (tid == 0) { dstt[0] = sh[0] + sh[1] + sh[2] + sh[3]; }
  } else {
    int idx = (blockIdx.x - 1) * 256 + threadIdx.x;   // [0, NM*HALF)
    if (idx < NM * HALF) {
      int m = idx / HALF, l = idx % HALF;
      double freq = (double)freqp[0];
      double t = -1.0 + 2.0 * (double)l / 2047.0;
      double phi = 6.2831853071795864769 * freq * t;
      double ang = (double)(m + 1) * phi * 0.25;
      double sv, cv;
      sincos(ang, &sv, &cv);
      float4 v;
      v.x = (float)fmax(log2(fabs(cv)), -1.0e4);
      v.y = (float)fmax(log2(fabs(sv)), -1.0e4);
      v.z = (float)sin(phi);
      v.w = 0.0f;
      reinterpret_cast<float4*>(fws + OFF_TAB)[m * HALF + l] = v;
    }
    if (blockIdx.x == 1 && threadIdx.x < NG) {
      float g = grid20(threadIdx.x);
      fws[OFF_G20 + threadIdx.x] = g;
      fws[OFF_R20 + threadIdx.x] = -1.0f / g;
    }
  }
}

// ---------------- K2: coarse lsum table ------------------------------------
// thread = (combo, l): lsum = log2(exp2(n2*lc) + exp2(n3*ls))
__global__ __launch_bounds__(256) void k_ctab(const float* __restrict__ fws,
                                              float* __restrict__ ctab) {
  int idx = blockIdx.x * 256 + threadIdx.x;   // [0, 4000*1024)
  int combo = idx >> 10, l = idx & 1023;
  int m = combo / (NG * NG);
  int i23 = combo % (NG * NG);
  float n2 = fws[OFF_G20 + i23 / NG];
  float n3 = fws[OFF_G20 + i23 % NG];
  float4 tb = reinterpret_cast<const float4*>(fws + OFF_TAB)[m * HALF + l];
  ctab[idx] = LOG2F(EXP2F(n2 * tb.x) + EXP2F(n3 * tb.y));
}

// ---------------- K3: coarse scan ------------------------------------------
// block = one combo; wave w owns i1 in [w*5, w*5+5). Independent exp2 only.
__global__ __launch_bounds__(256) void k_coarse(const float* __restrict__ fws,
                                                const double* __restrict__ dstt,
                                                double* __restrict__ bv,
                                                int* __restrict__ bt) {
  int tid = threadIdx.x;
  int lane = tid & 63, w = tid >> 6;
  int combo = blockIdx.x;
  int m = combo / (NG * NG);
  int i23 = combo % (NG * NG);

  float rq[5];
#pragma unroll
  for (int q = 0; q < 5; q++) rq[q] = fws[OFF_R20 + w * 5 + q];

  const float* lrow = fws + OFF_CTAB + combo * HALF;
  const float2* sc = reinterpret_cast<const float2*>(fws + OFF_SC);

  float sgg[5], sgt[5];
#pragma unroll
  for (int q = 0; q < 5; q++) { sgg[q] = 0.0f; sgt[q] = 0.0f; }

  for (int it = 0; it < 16; ++it) {
    int l = lane + it * 64;
    float lsum = lrow[l];
    float2 s = sc[l];
#pragma unroll
    for (int q = 0; q < 5; q++) {
      float e = EXP2F(rq[q] * lsum);
      float e2 = e * e;
      sgg[q] = fmaf(e2, s.x, sgg[q]);
      sgt[q] = fmaf(e, s.y, sgt[q]);
    }
  }

#pragma unroll
  for (int q = 0; q < 5; q++) {
    for (int o = 32; o > 0; o >>= 1) {
      sgg[q] += __shfl_down(sgg[q], o);
      sgt[q] += __shfl_down(sgt[q], o);
    }
  }

  __shared__ double sv[4];
  __shared__ int st[4];
  if (lane == 0) {
    double sum_tt = dstt[0];
    double best = 1e300; int bts = 0x7fffffff;
#pragma unroll
    for (int q = 0; q < 5; q++) {
      double mse = mse_from(2.0 * (double)sgg[q], (double)sgt[q], sum_tt);
      int t = (m * NG + w * 5 + q) * (NG * NG) + i23;
      if (mse < best) { best = mse; bts = t; }
    }
    sv[w] = best; st[w] = bts;
  }
  __syncthreads();
  if (tid == 0) {
    double best = sv[0]; int bts = st[0];
    for (int k = 1; k < 4; k++)
      if (sv[k] < best || (sv[k] == best && st[k] < bts)) { best = sv[k]; bts = st[k]; }
    bv[blockIdx.x] = best; bt[blockIdx.x] = bts;
  }
}

// ---------------- K4: coarse argmin + fine grid constants ------------------
__global__ __launch_bounds__(256) void k_cmin(const double* __restrict__ bvc,
                                              const int* __restrict__ btc,
                                              float* __restrict__ fws,
                                              int* __restrict__ im) {
  __shared__ double sv[4];
  __shared__ int st[4];
  double v = 1e300; int t = 0x7fffffff;
  for (int i = threadIdx.x; i < NCC; i += 256) {
    double ov = bvc[i]; int ot = btc[i];
    if (ov < v || (ov == v && ot < t)) { v = ov; t = ot; }
  }
  vt_block_merge(v, t, sv, st);
  if (threadIdx.x == 0) {
    int ci = t;
    int m  = ci / (NG * NG * NG);
    int rr = ci % (NG * NG * NG);
    int i1 = rr / (NG * NG);
    int i23 = rr % (NG * NG);
    float cn1 = grid20(i1), cn2 = grid20(i23 / NG), cn3 = grid20(i23 % NG);
    im[0] = m;
    for (int j = 0; j < NF; j++) {
      float n1 = finev(cn1, j);
      fws[OFF_N1F + j] = n1;
      fws[OFF_N2F + j] = finev(cn2, j);
      fws[OFF_N3F + j] = finev(cn3, j);
      fws[OFF_RF  + j] = -1.0f / n1;
    }
  }
}

// ---------------- K5: fine lsum table --------------------------------------
__global__ __launch_bounds__(256) void k_ftab(const float* __restrict__ fws,
                                              const int* __restrict__ im,
                                              float* __restrict__ ftab) {
  int idx = blockIdx.x * 256 + threadIdx.x;   // [0, 900*1024)
  int fc = idx >> 10, l = idx & 1023;
  int m = im[0];
  float n2 = fws[OFF_N2F + fc / NF];
  float n3 = fws[OFF_N3F + fc % NF];
  float4 tb = reinterpret_cast<const float4*>(fws + OFF_TAB)[m * HALF + l];
  ftab[idx] = LOG2F(EXP2F(n2 * tb.x) + EXP2F(n3 * tb.y));
}

// ---------------- K6: fine scan --------------------------------------------
// wave-job gwid in [0,4500): fc = gwid/5, j1ch = gwid%5 (6 j1 each)
__global__ __launch_bounds__(256) void k_fine(const float* __restrict__ fws,
                                              const double* __restrict__ dstt,
                                              double* __restrict__ bvf,
                                              int* __restrict__ btf) {
  int tid = threadIdx.x;
  int lane = tid & 63, w = tid >> 6;
  int gwid = blockIdx.x * 4 + w;
  int fc = gwid / 5;
  int j1ch = gwid % 5;

  float rq[6];
#pragma unroll
  for (int q = 0; q < 6; q++) rq[q] = fws[OFF_RF + j1ch * 6 + q];

  const float* lrow = fws + OFF_FTAB + fc * HALF;
  const float2* sc = reinterpret_cast<const float2*>(fws + OFF_SC);

  float sgg[6], sgt[6];
#pragma unroll
  for (int q = 0; q < 6; q++) { sgg[q] = 0.0f; sgt[q] = 0.0f; }

  for (int it = 0; it < 16; ++it) {
    int l = lane + it * 64;
    float lsum = lrow[l];
    float2 s = sc[l];
#pragma unroll
    for (int q = 0; q < 6; q++) {
      float e = EXP2F(rq[q] * lsum);
      float e2 = e * e;
      sgg[q] = fmaf(e2, s.x, sgg[q]);
      sgt[q] = fmaf(e, s.y, sgt[q]);
    }
  }

#pragma unroll
  for (int q = 0; q < 6; q++) {
    for (int o = 32; o > 0; o >>= 1) {
      sgg[q] += __shfl_down(sgg[q], o);
      sgt[q] += __shfl_down(sgt[q], o);
    }
  }

  __shared__ double sv[4];
  __shared__ int st[4];
  if (lane == 0) {
    double sum_tt = dstt[0];
    double best = 1e300; int bts = 0x7fffffff;
#pragma unroll
    for (int q = 0; q < 6; q++) {
      double mse = mse_from(2.0 * (double)sgg[q], (double)sgt[q], sum_tt);
      int t = (j1ch * 6 + q) * (NF * NF) + fc;
      if (mse < best) { best = mse; bts = t; }
    }
    sv[w] = best; st[w] = bts;
  }
  __syncthreads();
  if (tid == 0) {
    double best = sv[0]; int bts = st[0];
    for (int k = 1; k < 4; k++)
      if (sv[k] < best || (sv[k] == best && st[k] < bts)) { best = sv[k]; bts = st[k]; }
    bvf[blockIdx.x] = best; btf[blockIdx.x] = bts;
  }
}

// ---------------- K7: final fine argmin + emit -----------------------------
__global__ __launch_bounds__(256) void k_outN(const double* __restrict__ bvf,
                                              const int* __restrict__ btf,
                                              const float* __restrict__ fws,
                                              const int* __restrict__ im,
                                              float* __restrict__ out) {
  __shared__ double sv[4];
  __shared__ int st[4];
  double v = 1e300; int t = 0x7fffffff;
  for (int i = threadIdx.x; i < NFB; i += 256) {
    double ov = bvf[i]; int ot = btf[i];
    if (ov < v || (ov == v && ot < t)) { v = ov; t = ot; }
  }
  vt_block_merge(v, t, sv, st);
  if (threadIdx.x == 0) {
    int f1 = t / (NF * NF);
    int fc = t % (NF * NF);
    out[0] = (float)(im[0] + 1);
    out[1] = fws[OFF_N1F + f1];
    out[2] = fws[OFF_N2F + fc / NF];
    out[3] = fws[OFF_N3F + fc % NF];
  }
}

// ================== fallback path (round-6 structure) ======================
__global__ __launch_bounds__(256, 1) void kb_coarse(const float* __restrict__ fws,
                                                    const double* __restrict__ dstt,
                                                    double* __restrict__ bv,
                                                    int* __restrict__ bt) {
  int tid = threadIdx.x;
  int gwid = (blockIdx.x * 256 + tid) >> 6;
  int lane = tid & 63, w = tid >> 6;
  int combo = gwid >> 1, i1ch = gwid & 1;
  int m = combo / (NG * NG);
  int i23 = combo % (NG * NG);
  float n2 = fws[OFF_G20 + i23 / NG], n3 = fws[OFF_G20 + i23 % NG];
  float r[10];
#pragma unroll
  for (int q = 0; q < 10; q++) r[q] = fws[OFF_R20 + i1ch * 10 + q];
  const float4* tab = reinterpret_cast<const float4*>(fws + OFF_TAB) + m * HALF;
  const float* td = fws + OFF_TD;
  float sgg[10], sgt[10];
#pragma unroll
  for (int q = 0; q < 10; q++) { sgg[q] = 0.0f; sgt[q] = 0.0f; }
  for (int it = 0; it < 16; ++it) {
    int l = lane + it * 64;
    float4 tb = tab[l];
    float tdv = td[l];
    float lsum = LOG2F(EXP2F(n2 * tb.x) + EXP2F(n3 * tb.y));
    float spv = tb.z;
#pragma unroll
    for (int q = 0; q < 10; q++) {
      float g = EXP2F(r[q] * lsum) * spv;
      sgg[q] = fmaf(g, g, sgg[q]);
      sgt[q] = fmaf(g, tdv, sgt[q]);
    }
  }
#pragma unroll
  for (int q = 0; q < 10; q++) {
    for (int o = 32; o > 0; o >>= 1) {
      sgg[q] += __shfl_down(sgg[q], o);
      sgt[q] += __shfl_down(sgt[q], o);
    }
  }
  __shared__ double sv[4];
  __shared__ int st[4];
  if (lane == 0) {
    double sum_tt = dstt[0];
    double best = 1e300; int bts = 0x7fffffff;
#pragma unroll
    for (int q = 0; q < 10; q++) {
      double mse = mse_from(2.0 * (double)sgg[q], (double)sgt[q], sum_tt);
      if (mse < best) { best = mse; bts = (m * NG + i1ch * 10 + q) * (NG * NG) + i23; }
    }
    sv[w] = best; st[w] = bts;
  }
  __syncthreads();
  if (tid == 0) {
    double best = sv[0]; int bts = st[0];
    for (int k = 1; k < 4; k++)
      if (sv[k] < best || (sv[k] == best && st[k] < bts)) { best = sv[k]; bts = st[k]; }
    bv[blockIdx.x] = best; bt[blockIdx.x] = bts;
  }
}

__global__ __launch_bounds__(256, 1) void kb_fine(const float* __restrict__ fws,
                                                  const double* __restrict__ dstt,
                                                  const double* __restrict__ bvc,
                                                  const int* __restrict__ btc,
                                                  double* __restrict__ bvf,
                                                  int* __restrict__ btf) {
  __shared__ double sv[4];
  __shared__ int st[4];
  __shared__ int s_ci;
  {
    double v = 1e300; int t = 0x7fffffff;
    for (int i = threadIdx.x; i < 2000; i += 256) {
      double ov = bvc[i]; int ot = btc[i];
      if (ov < v || (ov == v && ot < t)) { v = ov; t = ot; }
    }
    vt_block_merge(v, t, sv, st);
    if (threadIdx.x == 0) s_ci = t;
  }
  __syncthreads();
  int ci = s_ci;
  int m  = ci / (NG * NG * NG);
  int rr = ci % (NG * NG * NG);
  float cn1 = grid20(rr / (NG * NG));
  float cn2 = grid20((rr / NG) % NG);
  float cn3 = grid20(rr % NG);

  int tid = threadIdx.x;
  int gwid = (blockIdx.x * 256 + tid) >> 6;
  int lane = tid & 63, w = tid >> 6;
  int fc = gwid / 5;
  int j1ch = gwid % 5;
  float n2 = finev(cn2, fc / NF), n3 = finev(cn3, fc % NF);
  float r[6];
#pragma unroll
  for (int q = 0; q < 6; q++) r[q] = -1.0f / finev(cn1, j1ch * 6 + q);
  const float4* tab = reinterpret_cast<const float4*>(fws + OFF_TAB) + m * HALF;
  const float* td = fws + OFF_TD;
  float sgg[6], sgt[6];
#pragma unroll
  for (int q = 0; q < 6; q++) { sgg[q] = 0.0f; sgt[q] = 0.0f; }
  for (int it = 0; it < 16; ++it) {
    int l = lane + it * 64;
    float4 tb = tab[l];
    float tdv = td[l];
    float lsum = LOG2F(EXP2F(n2 * tb.x) + EXP2F(n3 * tb.y));
    float spv = tb.z;
#pragma unroll
    for (int q = 0; q < 6; q++) {
      float g = EXP2F(r[q] * lsum) * spv;
      sgg[q] = fmaf(g, g, sgg[q]);
      sgt[q] = fmaf(g, tdv, sgt[q]);
    }
  }
#pragma unroll
  for (int q = 0; q < 6; q++) {
    for (int o = 32; o > 0; o >>= 1) {
      sgg[q] += __shfl_down(sgg[q], o);
      sgt[q] += __shfl_down(sgt[q], o);
    }
  }
  __syncthreads();
  if (lane == 0) {
    double sum_tt = dstt[0];
    double best = 1e300; int bts = 0x7fffffff;
#pragma unroll
    for (int q = 0; q < 6; q++) {
      double mse = mse_from(2.0 * (double)sgg[q], (double)sgt[q], sum_tt);
      if (mse < best) { best = mse; bts = (j1ch * 6 + q) * (NF * NF) + fc; }
    }
    sv[w] = best; st[w] = bts;
  }
  __syncthreads();
  if (tid == 0) {
    double best = sv[0]; int bts = st[0];
    for (int k = 1; k < 4; k++)
      if (sv[k] < best || (sv[k] == best && st[k] < bts)) { best = sv[k]; bts = st[k]; }
    bvf[blockIdx.x] = best; btf[blockIdx.x] = bts;
  }
}

__global__ __launch_bounds__(256) void kb_out(const double* __restrict__ bvc,
                                              const int* __restrict__ btc,
                                              const double* __restrict__ bvf,
                                              const int* __restrict__ btf,
                                              float* __restrict__ out) {
  __shared__ double sv[4];
  __shared__ int st[4];
  __shared__ int s_ci;
  {
    double v = 1e300; int t = 0x7fffffff;
    for (int i = threadIdx.x; i < 2000; i += 256) {
      double ov = bvc[i]; int ot = btc[i];
      if (ov < v || (ov == v && ot < t)) { v = ov; t = ot; }
    }
    vt_block_merge(v, t, sv, st);
    if (threadIdx.x == 0) s_ci = t;
  }
  __syncthreads();
  {
    double v = 1e300; int t = 0x7fffffff;
    for (int i = threadIdx.x; i < NFB; i += 256) {
      double ov = bvf[i]; int ot = btf[i];
      if (ov < v || (ov == v && ot < t)) { v = ov; t = ot; }
    }
    vt_block_merge(v, t, sv, st);
    if (threadIdx.x == 0) {
      int ci = s_ci;
      int m  = ci / (NG * NG * NG);
      int rr = ci % (NG * NG * NG);
      float cn1 = grid20(rr / (NG * NG));
      float cn2 = grid20((rr / NG) % NG);
      float cn3 = grid20(rr % NG);
      int fi = t;
      int f1 = fi / (NF * NF), f2 = (fi / NF) % NF, f3 = fi % NF;
      out[0] = (float)(m + 1);
      out[1] = finev(cn1, f1);
      out[2] = finev(cn2, f2);
      out[3] = finev(cn3, f3);
    }
  }
}

extern "C" void kernel_launch(void* const* d_in, const int* in_sizes, int n_in,
                              void* d_out, int out_size, void* d_ws, size_t ws_size,
                              hipStream_t stream) {
  const float* x = (const float*)d_in[0];
  const int* freqp = (const int*)d_in[1];
  float* out = (float*)d_out;
  float* fws = (float*)d_ws;

  const size_t needed = (size_t)OFF_DWS * 4 + (size_t)(1 + NCC + NFB) * 8
                      + (size_t)(NCC + NFB + 1) * 4 + 64;

  if (ws_size >= needed) {
    float* ctab = fws + OFF_CTAB;
    float* ftab = fws + OFF_FTAB;
    double* D0 = (double*)(fws + OFF_DWS);
    double* dstt = D0;                 // [1]
    double* bvc = D0 + 1;              // NCC
    double* bvf = bvc + NCC;           // NFB
    int* btc = (int*)(bvf + NFB);      // NCC
    int* btf = btc + NCC;              // NFB
    int* im  = btf + NFB;              // 1

    hipLaunchKernelGGL(k_init,   dim3(1 + (NM * HALF + 255) / 256), dim3(256), 0, stream,
                       x, freqp, fws, dstt);
    hipLaunchKernelGGL(k_ctab,   dim3(NCC * HALF / 256), dim3(256), 0, stream, fws, ctab);
    hipLaunchKernelGGL(k_coarse, dim3(NCC),  dim3(256), 0, stream, fws, dstt, bvc, btc);
    hipLaunchKernelGGL(k_cmin,   dim3(1),    dim3(256), 0, stream, bvc, btc, fws, im);
    hipLaunchKernelGGL(k_ftab,   dim3(900 * HALF / 256), dim3(256), 0, stream, fws, im, ftab);
    hipLaunchKernelGGL(k_fine,   dim3(NFB),  dim3(256), 0, stream, fws, dstt, bvf, btf);
    hipLaunchKernelGGL(k_outN,   dim3(1),    dim3(256), 0, stream, bvf, btf, fws, im, out);
  } else {
    // fallback: round-6 structure within ~210 KB
    double* D0 = (double*)(fws + OFF_CTAB);   // dws right after constants
    double* dstt = D0;                 // [1]
    double* bvc = D0 + 1;              // 2000
    double* bvf = bvc + 2000;          // NFB
    int* btc = (int*)(bvf + NFB);      // 2000
    int* btf = btc + 2000;             // NFB

    hipLaunchKernelGGL(k_init,    dim3(1 + (NM * HALF + 255) / 256), dim3(256), 0, stream,
                       x, freqp, fws, dstt);
    hipLaunchKernelGGL(kb_coarse, dim3(2000), dim3(256), 0, stream, fws, dstt, bvc, btc);
    hipLaunchKernelGGL(kb_fine,   dim3(NFB),  dim3(256), 0, stream, fws, dstt, bvc, btc, bvf, btf);
    hipLaunchKernelGGL(kb_out,    dim3(1),    dim3(256), 0, stream, bvc, btc, bvf, btf, out);
  }
}

// Round 9
// 79.899 us; speedup vs baseline: 1.2974x; 1.0358x over previous
//
#include <hip/hip_runtime.h>

#define L    2048
#define HALF 1024
#define NM   10
#define NG   20
#define NF   30

#define NCC  4000   // coarse blocks = combos (m,i2,i3)
#define NFC  900    // fine blocks = combos (j2,j3)

// ---- float workspace layout ----
#define OFF_SC   0                      // float2 sc[1024] = {sin^2, sin*td}
#define OFF_TAB  2048                   // float2 tab[NM*HALF] = {lc, ls}
#define OFF_G20  (2048 + 2*NM*HALF)     // 22528: grid20[20]
#define OFF_R20  (OFF_G20 + 20)         // -1/grid20 [20]
#define OFF_END  (OFF_R20 + 20)         // 22568 floats -> 90272 bytes (8-aligned)

#define EXP2F(x) __builtin_amdgcn_exp2f(x)
#define LOG2F(x) __builtin_amdgcn_logf(x)

// VALU-only exp2 (Cephes minimax, rel err ~2e-8); y in [-10, 60] here.
__device__ __forceinline__ float fast_exp2(float x) {
  float n = __builtin_rintf(x);
  float f = x - n;
  float p = 1.535336188319500e-4f;
  p = fmaf(p, f, 1.339887440266574e-3f);
  p = fmaf(p, f, 9.618437357674640e-3f);
  p = fmaf(p, f, 5.550332471162809e-2f);
  p = fmaf(p, f, 2.402264791363012e-1f);
  p = fmaf(p, f, 6.931472028550421e-1f);
  p = fmaf(p, f, 1.0f);
  return __builtin_ldexpf(p, (int)n);
}

__device__ __forceinline__ float grid20(int i) {
  double e = -1.0 + 2.0 * (double)i / 19.0;
  return (float)exp2(e * 3.3219280948873623478703194294894);
}
__device__ __forceinline__ float finev(float c, int j) {
  return (float)((double)c * 0.8 + (double)j * ((double)c * 0.4 / 29.0));
}
__device__ __forceinline__ double mse_from(double sgg2, double sgt, double sum_tt) {
  double S = sgg2; if (S < 0.0) S = 0.0;
  double d = sqrt(S / (double)(L - 1)) + 1e-6;
  return (S / (d * d) - 2.0 * sgt / d + sum_tt) / (double)L;
}
__device__ __forceinline__ void vt_wave_reduce(double& v, int& t) {
  for (int o = 32; o > 0; o >>= 1) {
    double ov = __shfl_down(v, o);
    int ot = __shfl_down(t, o);
    if (ov < v || (ov == v && ot < t)) { v = ov; t = ot; }
  }
}
__device__ __forceinline__ void vt_block_merge(double& v, int& t, double* sv, int* st) {
  int lane = threadIdx.x & 63, w = threadIdx.x >> 6;
  vt_wave_reduce(v, t);
  if (lane == 0) { sv[w] = v; st[w] = t; }
  __syncthreads();
  if (threadIdx.x == 0) {
    for (int k = 1; k < 4; k++)
      if (sv[k] < v || (sv[k] == v && st[k] < t)) { v = sv[k]; t = st[k]; }
  }
}

// ---------------- K1: setup (block 0) + tables (blocks 1..40) --------------
__global__ __launch_bounds__(256) void k_init(const float* __restrict__ x,
                                              const int* __restrict__ freqp,
                                              float* __restrict__ fws,
                                              double* __restrict__ dstt) {
  if (blockIdx.x == 0) {
    int tid = threadIdx.x;
    int lane = tid & 63, w = tid >> 6;
    __shared__ double sh[8];
    __shared__ double s_mean, s_d;

    double sx = 0.0, sxx = 0.0;
    for (int l = tid; l < L; l += 256) {
      double v = (double)x[l];
      sx += v; sxx += v * v;
    }
    for (int o = 32; o > 0; o >>= 1) { sx += __shfl_down(sx, o); sxx += __shfl_down(sxx, o); }
    if (lane == 0) { sh[w] = sx; sh[4 + w] = sxx; }
    __syncthreads();
    if (tid == 0) {
      sx = sh[0] + sh[1] + sh[2] + sh[3];
      sxx = sh[4] + sh[5] + sh[6] + sh[7];
      double mean = sx / (double)L;
      double S = sxx - sx * sx / (double)L; if (S < 0.0) S = 0.0;
      s_mean = mean; s_d = sqrt(S / (double)(L - 1)) + 1e-6;
    }
    __syncthreads();
    double mean = s_mean, d = s_d;
    double freq = (double)freqp[0];

    double stt = 0.0;
    for (int l = tid; l < HALF; l += 256) {
      float tva = (float)(((double)x[l] - mean) / d);
      float tvb = (float)(((double)x[L - 1 - l] - mean) / d);
      float tdv = tva - tvb;
      double t = -1.0 + 2.0 * (double)l / 2047.0;
      float spv = (float)sin(6.2831853071795864769 * freq * t);
      float2 scv; scv.x = spv * spv; scv.y = spv * tdv;
      reinterpret_cast<float2*>(fws + OFF_SC)[l] = scv;
      stt += (double)tva * (double)tva + (double)tvb * (double)tvb;
    }
    for (int o = 32; o > 0; o >>= 1) { stt += __shfl_down(stt, o); }
    __syncthreads();
    if (lane == 0) { sh[w] = stt; }
    __syncthreads();
    if (tid == 0) { dstt[0] = sh[0] + sh[1] + sh[2] + sh[3]; }
  } else {
    int idx = (blockIdx.x - 1) * 256 + threadIdx.x;   // [0, NM*HALF)
    if (idx < NM * HALF) {
      int m = idx / HALF, l = idx % HALF;
      double freq = (double)freqp[0];
      double t = -1.0 + 2.0 * (double)l / 2047.0;
      double phi = 6.2831853071795864769 * freq * t;
      double ang = (double)(m + 1) * phi * 0.25;
      double sv, cv;
      sincos(ang, &sv, &cv);
      float2 v;
      v.x = (float)fmax(log2(fabs(cv)), -1.0e4);
      v.y = (float)fmax(log2(fabs(sv)), -1.0e4);
      reinterpret_cast<float2*>(fws + OFF_TAB)[m * HALF + l] = v;
    }
    if (blockIdx.x == 1 && threadIdx.x < NG) {
      float g = grid20(threadIdx.x);
      fws[OFF_G20 + threadIdx.x] = g;
      fws[OFF_R20 + threadIdx.x] = -1.0f / g;
    }
  }
}

// ---------------- K2: coarse scan (lsum->LDS, poly exp2 in q-loop) ---------
// block = combo (m,i2,i3); wave w owns i1 in [5w, 5w+5)
__global__ __launch_bounds__(256) void k_coarse(const float* __restrict__ fws,
                                                const double* __restrict__ dstt,
                                                double* __restrict__ bv,
                                                int* __restrict__ bt) {
  __shared__ float lsum_s[HALF];
  __shared__ double sv[4];
  __shared__ int st[4];
  int tid = threadIdx.x, lane = tid & 63, w = tid >> 6;
  int combo = blockIdx.x;
  int m = combo / (NG * NG);
  int i23 = combo % (NG * NG);
  float n2 = fws[OFF_G20 + i23 / NG];
  float n3 = fws[OFF_G20 + i23 % NG];

  // phase 1: lsum row into LDS (raw trans)
  const float2* tab = reinterpret_cast<const float2*>(fws + OFF_TAB) + m * HALF;
#pragma unroll
  for (int k = 0; k < 4; k++) {
    int l = tid + k * 256;
    float2 t = tab[l];
    lsum_s[l] = LOG2F(EXP2F(n2 * t.x) + EXP2F(n3 * t.y));
  }
  __syncthreads();

  // phase 2: poly exp2 (VALU-only) — the A/B arm
  float rq[5];
#pragma unroll
  for (int q = 0; q < 5; q++) rq[q] = fws[OFF_R20 + w * 5 + q];
  const float2* sc = reinterpret_cast<const float2*>(fws + OFF_SC);

  float sgg[5], sgt[5];
#pragma unroll
  for (int q = 0; q < 5; q++) { sgg[q] = 0.0f; sgt[q] = 0.0f; }

  for (int it = 0; it < 16; ++it) {
    int l = lane + it * 64;
    float ls = lsum_s[l];
    float2 s = sc[l];
#pragma unroll
    for (int q = 0; q < 5; q++) {
      float e = fast_exp2(rq[q] * ls);
      float e2 = e * e;
      sgg[q] = fmaf(e2, s.x, sgg[q]);
      sgt[q] = fmaf(e, s.y, sgt[q]);
    }
  }

#pragma unroll
  for (int q = 0; q < 5; q++) {
    for (int o = 32; o > 0; o >>= 1) {
      sgg[q] += __shfl_down(sgg[q], o);
      sgt[q] += __shfl_down(sgt[q], o);
    }
  }

  if (lane == 0) {
    double sum_tt = dstt[0];
    double best = 1e300; int bts = 0x7fffffff;
#pragma unroll
    for (int q = 0; q < 5; q++) {
      double mse = mse_from(2.0 * (double)sgg[q], (double)sgt[q], sum_tt);
      int t = (m * NG + w * 5 + q) * (NG * NG) + i23;
      if (mse < best) { best = mse; bts = t; }
    }
    sv[w] = best; st[w] = bts;
  }
  __syncthreads();
  if (tid == 0) {
    double best = sv[0]; int bts = st[0];
    for (int k = 1; k < 4; k++)
      if (sv[k] < best || (sv[k] == best && st[k] < bts)) { best = sv[k]; bts = st[k]; }
    bv[blockIdx.x] = best; bt[blockIdx.x] = bts;
  }
}

// ---------------- K3: fine scan (in-block coarse argmin; raw trans q-loop) -
// block = fc (j2,j3); wave w owns j1 in [8w, 8w+cnt), cnt = {8,8,8,6}
__global__ __launch_bounds__(256) void k_fine(const float* __restrict__ fws,
                                              const double* __restrict__ dstt,
                                              const double* __restrict__ bvc,
                                              const int* __restrict__ btc,
                                              double* __restrict__ bvf,
                                              int* __restrict__ btf) {
  __shared__ float lsum_s[HALF];
  __shared__ double sv[4];
  __shared__ int st[4];
  __shared__ float s_cn[4];   // cn1, cn2, cn3, (m as float)

  // coarse argmin (all threads scan the 4000 block-results)
  {
    double v = 1e300; int t = 0x7fffffff;
    for (int i = threadIdx.x; i < NCC; i += 256) {
      double ov = bvc[i]; int ot = btc[i];
      if (ov < v || (ov == v && ot < t)) { v = ov; t = ot; }
    }
    vt_block_merge(v, t, sv, st);
    if (threadIdx.x == 0) {
      int ci = t;
      int m  = ci / (NG * NG * NG);
      int rr = ci % (NG * NG * NG);
      s_cn[0] = grid20(rr / (NG * NG));
      s_cn[1] = grid20((rr / NG) % NG);
      s_cn[2] = grid20(rr % NG);
      s_cn[3] = (float)m;
    }
  }
  __syncthreads();
  float cn1 = s_cn[0], cn2 = s_cn[1], cn3 = s_cn[2];
  int m = (int)s_cn[3];

  int tid = threadIdx.x, lane = tid & 63, w = tid >> 6;
  int fc = blockIdx.x;
  int j2 = fc / NF, j3 = fc % NF;
  float n2 = finev(cn2, j2), n3 = finev(cn3, j3);

  // phase 1: lsum row into LDS (raw trans)
  const float2* tab = reinterpret_cast<const float2*>(fws + OFF_TAB) + m * HALF;
#pragma unroll
  for (int k = 0; k < 4; k++) {
    int l = tid + k * 256;
    float2 t = tab[l];
    lsum_s[l] = LOG2F(EXP2F(n2 * t.x) + EXP2F(n3 * t.y));
  }
  __syncthreads();

  // phase 2: raw v_exp (the other A/B arm)
  int base = w * 8;
  int cnt = (base + 8 <= NF) ? 8 : (NF - base);   // 8,8,8,6
  float rq[8];
#pragma unroll
  for (int q = 0; q < 8; q++) {
    int j1 = base + q; if (j1 > NF - 1) j1 = NF - 1;
    rq[q] = -1.0f / finev(cn1, j1);
  }
  const float2* sc = reinterpret_cast<const float2*>(fws + OFF_SC);

  float sgg[8], sgt[8];
#pragma unroll
  for (int q = 0; q < 8; q++) { sgg[q] = 0.0f; sgt[q] = 0.0f; }

  for (int it = 0; it < 16; ++it) {
    int l = lane + it * 64;
    float ls = lsum_s[l];
    float2 s = sc[l];
#pragma unroll
    for (int q = 0; q < 8; q++) {
      float e = EXP2F(rq[q] * ls);
      float e2 = e * e;
      sgg[q] = fmaf(e2, s.x, sgg[q]);
      sgt[q] = fmaf(e, s.y, sgt[q]);
    }
  }

#pragma unroll
  for (int q = 0; q < 8; q++) {
    for (int o = 32; o > 0; o >>= 1) {
      sgg[q] += __shfl_down(sgg[q], o);
      sgt[q] += __shfl_down(sgt[q], o);
    }
  }

  __syncthreads();   // reuse sv/st
  if (lane == 0) {
    double sum_tt = dstt[0];
    double best = 1e300; int bts = 0x7fffffff;
#pragma unroll
    for (int q = 0; q < 8; q++) {
      if (q < cnt) {
        double mse = mse_from(2.0 * (double)sgg[q], (double)sgt[q], sum_tt);
        int t = (base + q) * (NF * NF) + fc;
        if (mse < best) { best = mse; bts = t; }
      }
    }
    sv[w] = best; st[w] = bts;
  }
  __syncthreads();
  if (tid == 0) {
    double best = sv[0]; int bts = st[0];
    for (int k = 1; k < 4; k++)
      if (sv[k] < best || (sv[k] == best && st[k] < bts)) { best = sv[k]; bts = st[k]; }
    bvf[blockIdx.x] = best; btf[blockIdx.x] = bts;
  }
}

// ---------------- K4: final argmins + emit ---------------------------------
__global__ __launch_bounds__(256) void k_out(const double* __restrict__ bvc,
                                             const int* __restrict__ btc,
                                             const double* __restrict__ bvf,
                                             const int* __restrict__ btf,
                                             float* __restrict__ out) {
  __shared__ double sv[4];
  __shared__ int st[4];
  __shared__ int s_ci;
  {
    double v = 1e300; int t = 0x7fffffff;
    for (int i = threadIdx.x; i < NCC; i += 256) {
      double ov = bvc[i]; int ot = btc[i];
      if (ov < v || (ov == v && ot < t)) { v = ov; t = ot; }
    }
    vt_block_merge(v, t, sv, st);
    if (threadIdx.x == 0) s_ci = t;
  }
  __syncthreads();
  {
    double v = 1e300; int t = 0x7fffffff;
    for (int i = threadIdx.x; i < NFC; i += 256) {
      double ov = bvf[i]; int ot = btf[i];
      if (ov < v || (ov == v && ot < t)) { v = ov; t = ot; }
    }
    vt_block_merge(v, t, sv, st);
    if (threadIdx.x == 0) {
      int ci = s_ci;
      int m  = ci / (NG * NG * NG);
      int rr = ci % (NG * NG * NG);
      float cn1 = grid20(rr / (NG * NG));
      float cn2 = grid20((rr / NG) % NG);
      float cn3 = grid20(rr % NG);
      int fi = t;
      int f1 = fi / (NF * NF);
      int fc = fi % (NF * NF);
      out[0] = (float)(m + 1);
      out[1] = finev(cn1, f1);
      out[2] = finev(cn2, fc / NF);
      out[3] = finev(cn3, fc % NF);
    }
  }
}

extern "C" void kernel_launch(void* const* d_in, const int* in_sizes, int n_in,
                              void* d_out, int out_size, void* d_ws, size_t ws_size,
                              hipStream_t stream) {
  const float* x = (const float*)d_in[0];
  const int* freqp = (const int*)d_in[1];
  float* out = (float*)d_out;
  float* fws = (float*)d_ws;

  double* D0  = (double*)(fws + OFF_END);   // byte offset 90272, 8-aligned
  double* dstt = D0;                        // [1]
  double* bvc = D0 + 1;                     // NCC
  double* bvf = bvc + NCC;                  // NFC
  int* btc = (int*)(bvf + NFC);             // NCC
  int* btf = btc + NCC;                     // NFC

  hipLaunchKernelGGL(k_init,   dim3(1 + (NM * HALF + 255) / 256), dim3(256), 0, stream,
                     x, freqp, fws, dstt);
  hipLaunchKernelGGL(k_coarse, dim3(NCC), dim3(256), 0, stream, fws, dstt, bvc, btc);
  hipLaunchKernelGGL(k_fine,   dim3(NFC), dim3(256), 0, stream, fws, dstt, bvc, btc, bvf, btf);
  hipLaunchKernelGGL(k_out,    dim3(1),   dim3(256), 0, stream, bvc, btc, bvf, btf, out);
}

// Round 10
// 69.172 us; speedup vs baseline: 1.4987x; 1.1551x over previous
//
#include <hip/hip_runtime.h>

#define L    2048
#define HALF 1024
#define NM   10
#define NG   20
#define NF   30

#define NCC  4000   // coarse blocks = combos (m,i2,i3)
#define NFC  900    // fine blocks = combos (j2,j3)
#define NBC  313    // ceil(80000/256)  k_cfin blocks
#define NBF  106    // ceil(27000/256)  k_ffin blocks

// ---- float workspace layout (float indices) ----
#define OFF_SC   0                        // float2 sc[1024] = {sin^2, sin*td}
#define OFF_TAB  2048                     // float2 tab[NM*HALF] = {lc, ls}
#define OFF_G20  (2048 + 2*NM*HALF)       // 22528: grid20[20]
#define OFF_R20  (OFF_G20 + 20)           // -1/grid20 [20]
#define OFF_PC   (OFF_R20 + 20)           // float2 part_c[80000]  (160000 floats)
#define OFF_PF   (OFF_PC + 160000)        // float2 part_f[27000]  (54000 floats)
#define OFF_DWS  (OFF_PF + 54000)         // 236568 floats -> byte 946272 (%8==0)

#define EXP2F(x) __builtin_amdgcn_exp2f(x)
#define LOG2F(x) __builtin_amdgcn_logf(x)

__device__ __forceinline__ float grid20(int i) {
  double e = -1.0 + 2.0 * (double)i / 19.0;
  return (float)exp2(e * 3.3219280948873623478703194294894);
}
__device__ __forceinline__ float finev(float c, int j) {
  return (float)((double)c * 0.8 + (double)j * ((double)c * 0.4 / 29.0));
}
__device__ __forceinline__ double mse_from(double sgg2, double sgt, double sum_tt) {
  double S = sgg2; if (S < 0.0) S = 0.0;
  double d = sqrt(S / (double)(L - 1)) + 1e-6;
  return (S / (d * d) - 2.0 * sgt / d + sum_tt) / (double)L;
}
__device__ __forceinline__ void vt_wave_reduce(double& v, int& t) {
  for (int o = 32; o > 0; o >>= 1) {
    double ov = __shfl_down(v, o);
    int ot = __shfl_down(t, o);
    if (ov < v || (ov == v && ot < t)) { v = ov; t = ot; }
  }
}
__device__ __forceinline__ void vt_block_merge(double& v, int& t, double* sv, int* st) {
  int lane = threadIdx.x & 63, w = threadIdx.x >> 6;
  vt_wave_reduce(v, t);
  if (lane == 0) { sv[w] = v; st[w] = t; }
  __syncthreads();
  if (threadIdx.x == 0) {
    for (int k = 1; k < 4; k++)
      if (sv[k] < v || (sv[k] == v && st[k] < t)) { v = sv[k]; t = st[k]; }
  }
}

// ---------------- K1: setup (block 0) + tables (blocks 1..4, recurrence) ---
__global__ __launch_bounds__(256) void k_init(const float* __restrict__ x,
                                              const int* __restrict__ freqp,
                                              float* __restrict__ fws,
                                              double* __restrict__ dstt) {
  if (blockIdx.x == 0) {
    int tid = threadIdx.x;
    int lane = tid & 63, w = tid >> 6;
    __shared__ double sh[8];
    __shared__ double s_mean, s_d;

    double sx = 0.0, sxx = 0.0;
    for (int l = tid; l < L; l += 256) {
      double v = (double)x[l];
      sx += v; sxx += v * v;
    }
    for (int o = 32; o > 0; o >>= 1) { sx += __shfl_down(sx, o); sxx += __shfl_down(sxx, o); }
    if (lane == 0) { sh[w] = sx; sh[4 + w] = sxx; }
    __syncthreads();
    if (tid == 0) {
      sx = sh[0] + sh[1] + sh[2] + sh[3];
      sxx = sh[4] + sh[5] + sh[6] + sh[7];
      double mean = sx / (double)L;
      double S = sxx - sx * sx / (double)L; if (S < 0.0) S = 0.0;
      s_mean = mean; s_d = sqrt(S / (double)(L - 1)) + 1e-6;
    }
    __syncthreads();
    double mean = s_mean, d = s_d;
    double freq = (double)freqp[0];

    double stt = 0.0;
    for (int l = tid; l < HALF; l += 256) {
      float tva = (float)(((double)x[l] - mean) / d);
      float tvb = (float)(((double)x[L - 1 - l] - mean) / d);
      float tdv = tva - tvb;
      double t = -1.0 + 2.0 * (double)l / 2047.0;
      float spv = (float)sin(6.2831853071795864769 * freq * t);
      float2 scv; scv.x = spv * spv; scv.y = spv * tdv;
      reinterpret_cast<float2*>(fws + OFF_SC)[l] = scv;
      stt += (double)tva * (double)tva + (double)tvb * (double)tvb;
    }
    for (int o = 32; o > 0; o >>= 1) { stt += __shfl_down(stt, o); }
    __syncthreads();
    if (lane == 0) { sh[w] = stt; }
    __syncthreads();
    if (tid == 0) { dstt[0] = sh[0] + sh[1] + sh[2] + sh[3]; }
  } else {
    // blocks 1..4: one thread per l; sincos once, then 10 angle-addition steps
    int l = (blockIdx.x - 1) * 256 + threadIdx.x;   // [0, 1024)
    double freq = (double)freqp[0];
    double t = -1.0 + 2.0 * (double)l / 2047.0;
    double theta = 6.2831853071795864769 * freq * t * 0.25;   // phi/4
    double s1, c1;
    sincos(theta, &s1, &c1);
    double sk = s1, ck = c1;
    float2* tabp = reinterpret_cast<float2*>(fws + OFF_TAB);
#pragma unroll
    for (int m = 0; m < NM; ++m) {
      float2 v;
      v.x = fmaxf(LOG2F(fabsf((float)ck)), -1.0e4f);
      v.y = fmaxf(LOG2F(fabsf((float)sk)), -1.0e4f);
      tabp[m * HALF + l] = v;
      double sn = sk * c1 + ck * s1;
      double cn = ck * c1 - sk * s1;
      sk = sn; ck = cn;
    }
    if (blockIdx.x == 1 && threadIdx.x < NG) {
      float g = grid20(threadIdx.x);
      fws[OFF_G20 + threadIdx.x] = g;
      fws[OFF_R20 + threadIdx.x] = -1.0f / g;
    }
  }
}

// ---------------- K2: coarse scan — scalar accumulators only ---------------
// block = combo (m,i2,i3); LDS float4 row {lsum, sx, sy, 0}; wave w does
// i1 = w*5+sub sequentially (sub=0..4), 2 f32 accumulators live at a time.
__global__ __launch_bounds__(256) void k_coarse(const float* __restrict__ fws,
                                                float2* __restrict__ part) {
  __shared__ float4 row[HALF];   // 16 KB
  int tid = threadIdx.x, lane = tid & 63, w = tid >> 6;
  int combo = blockIdx.x;
  int m = combo / (NG * NG);
  int i23 = combo % (NG * NG);
  float n2 = fws[OFF_G20 + i23 / NG];
  float n3 = fws[OFF_G20 + i23 % NG];

  const float2* tab = reinterpret_cast<const float2*>(fws + OFF_TAB) + m * HALF;
  const float2* sc = reinterpret_cast<const float2*>(fws + OFF_SC);
#pragma unroll
  for (int k = 0; k < 4; k++) {
    int l = tid + k * 256;
    float2 tb = tab[l];
    float2 s = sc[l];
    float4 v;
    v.x = LOG2F(EXP2F(n2 * tb.x) + EXP2F(n3 * tb.y));
    v.y = s.x; v.z = s.y; v.w = 0.0f;
    row[l] = v;
  }
  __syncthreads();

  int base = combo * 20;
  for (int sub = 0; sub < 5; ++sub) {
    int i1 = w * 5 + sub;
    float r = fws[OFF_R20 + i1];
    float sgg = 0.0f, sgt = 0.0f;
#pragma unroll 4
    for (int it = 0; it < 16; ++it) {
      float4 v = row[lane + it * 64];
      float e = EXP2F(r * v.x);
      sgg = fmaf(e * e, v.y, sgg);
      sgt = fmaf(e, v.z, sgt);
    }
    for (int o = 32; o > 0; o >>= 1) {
      sgg += __shfl_down(sgg, o);
      sgt += __shfl_down(sgt, o);
    }
    if (lane == 0) part[base + i1] = make_float2(sgg, sgt);
  }
}

// ---------------- K3: coarse finalize (f64 mse) + argmin stage 1 -----------
__global__ __launch_bounds__(256) void k_cfin(const float* __restrict__ fws,
                                              const double* __restrict__ dstt,
                                              double* __restrict__ pv,
                                              int* __restrict__ pi) {
  int t = blockIdx.x * 256 + threadIdx.x;
  double best = 1e300; int bi = 0x7fffffff;
  if (t < NM * NG * NG * NG) {
    int m = t / (NG * NG * NG);
    int i1 = (t / (NG * NG)) % NG;
    int i23 = t % (NG * NG);
    float2 p = reinterpret_cast<const float2*>(fws + OFF_PC)[(m * 400 + i23) * 20 + i1];
    best = mse_from(2.0 * (double)p.x, (double)p.y, dstt[0]);
    bi = t;
  }
  __shared__ double sv[4];
  __shared__ int st[4];
  vt_block_merge(best, bi, sv, st);
  if (threadIdx.x == 0) { pv[blockIdx.x] = best; pi[blockIdx.x] = bi; }
}

// ---------------- K4: fine scan (in-block coarse argmin stage 2) -----------
// block = fc (j2,j3); wave w does j1 = w*8+sub sequentially (cnt 8,8,8,6)
__global__ __launch_bounds__(256) void k_fine(const float* __restrict__ fws,
                                              const double* __restrict__ pvc,
                                              const int* __restrict__ pic,
                                              float2* __restrict__ partf) {
  __shared__ float4 row[HALF];
  __shared__ double sv[4];
  __shared__ int st[4];
  __shared__ float s_cn[4];
  {
    double v = 1e300; int t = 0x7fffffff;
    for (int i = threadIdx.x; i < NBC; i += 256) {
      double ov = pvc[i]; int ot = pic[i];
      if (ov < v || (ov == v && ot < t)) { v = ov; t = ot; }
    }
    vt_block_merge(v, t, sv, st);
    if (threadIdx.x == 0) {
      int ci = t;
      int m  = ci / (NG * NG * NG);
      int rr = ci % (NG * NG * NG);
      s_cn[0] = grid20(rr / (NG * NG));
      s_cn[1] = grid20((rr / NG) % NG);
      s_cn[2] = grid20(rr % NG);
      s_cn[3] = (float)m;
    }
  }
  __syncthreads();
  float cn1 = s_cn[0], cn2 = s_cn[1], cn3 = s_cn[2];
  int m = (int)s_cn[3];

  int tid = threadIdx.x, lane = tid & 63, w = tid >> 6;
  int fc = blockIdx.x;
  float n2 = finev(cn2, fc / NF), n3 = finev(cn3, fc % NF);

  const float2* tab = reinterpret_cast<const float2*>(fws + OFF_TAB) + m * HALF;
  const float2* sc = reinterpret_cast<const float2*>(fws + OFF_SC);
#pragma unroll
  for (int k = 0; k < 4; k++) {
    int l = tid + k * 256;
    float2 tb = tab[l];
    float2 s = sc[l];
    float4 v;
    v.x = LOG2F(EXP2F(n2 * tb.x) + EXP2F(n3 * tb.y));
    v.y = s.x; v.z = s.y; v.w = 0.0f;
    row[l] = v;
  }
  __syncthreads();

  int base = fc * 30;
  int cnt = (w < 3) ? 8 : 6;
  for (int sub = 0; sub < cnt; ++sub) {
    int j1 = w * 8 + sub;
    float r = -1.0f / finev(cn1, j1);
    float sgg = 0.0f, sgt = 0.0f;
#pragma unroll 4
    for (int it = 0; it < 16; ++it) {
      float4 v = row[lane + it * 64];
      float e = EXP2F(r * v.x);
      sgg = fmaf(e * e, v.y, sgg);
      sgt = fmaf(e, v.z, sgt);
    }
    for (int o = 32; o > 0; o >>= 1) {
      sgg += __shfl_down(sgg, o);
      sgt += __shfl_down(sgt, o);
    }
    if (lane == 0) partf[base + j1] = make_float2(sgg, sgt);
  }
}

// ---------------- K5: fine finalize + argmin stage 1 -----------------------
__global__ __launch_bounds__(256) void k_ffin(const float* __restrict__ fws,
                                              const double* __restrict__ dstt,
                                              double* __restrict__ pv,
                                              int* __restrict__ pi) {
  int t = blockIdx.x * 256 + threadIdx.x;
  double best = 1e300; int bi = 0x7fffffff;
  if (t < NF * NF * NF) {
    int j1 = t / (NF * NF);
    int fc = t % (NF * NF);
    float2 p = reinterpret_cast<const float2*>(fws + OFF_PF)[fc * 30 + j1];
    best = mse_from(2.0 * (double)p.x, (double)p.y, dstt[0]);
    bi = t;
  }
  __shared__ double sv[4];
  __shared__ int st[4];
  vt_block_merge(best, bi, sv, st);
  if (threadIdx.x == 0) { pv[blockIdx.x] = best; pi[blockIdx.x] = bi; }
}

// ---------------- K6: final argmins + emit ---------------------------------
__global__ __launch_bounds__(256) void k_out(const double* __restrict__ pvc,
                                             const int* __restrict__ pic,
                                             const double* __restrict__ pvf,
                                             const int* __restrict__ pif,
                                             float* __restrict__ out) {
  __shared__ double sv[4];
  __shared__ int st[4];
  __shared__ int s_ci;
  {
    double v = 1e300; int t = 0x7fffffff;
    for (int i = threadIdx.x; i < NBC; i += 256) {
      double ov = pvc[i]; int ot = pic[i];
      if (ov < v || (ov == v && ot < t)) { v = ov; t = ot; }
    }
    vt_block_merge(v, t, sv, st);
    if (threadIdx.x == 0) s_ci = t;
  }
  __syncthreads();
  {
    double v = 1e300; int t = 0x7fffffff;
    for (int i = threadIdx.x; i < NBF; i += 256) {
      double ov = pvf[i]; int ot = pif[i];
      if (ov < v || (ov == v && ot < t)) { v = ov; t = ot; }
    }
    vt_block_merge(v, t, sv, st);
    if (threadIdx.x == 0) {
      int ci = s_ci;
      int m  = ci / (NG * NG * NG);
      int rr = ci % (NG * NG * NG);
      float cn1 = grid20(rr / (NG * NG));
      float cn2 = grid20((rr / NG) % NG);
      float cn3 = grid20(rr % NG);
      int fi = t;
      int f1 = fi / (NF * NF);
      int fc = fi % (NF * NF);
      out[0] = (float)(m + 1);
      out[1] = finev(cn1, f1);
      out[2] = finev(cn2, fc / NF);
      out[3] = finev(cn3, fc % NF);
    }
  }
}

extern "C" void kernel_launch(void* const* d_in, const int* in_sizes, int n_in,
                              void* d_out, int out_size, void* d_ws, size_t ws_size,
                              hipStream_t stream) {
  const float* x = (const float*)d_in[0];
  const int* freqp = (const int*)d_in[1];
  float* out = (float*)d_out;
  float* fws = (float*)d_ws;

  float2* part_c = reinterpret_cast<float2*>(fws + OFF_PC);
  float2* part_f = reinterpret_cast<float2*>(fws + OFF_PF);
  double* D0  = (double*)(fws + OFF_DWS);   // byte 946272, 8-aligned
  double* dstt = D0;                        // [1]
  double* pvc = D0 + 1;                     // NBC
  double* pvf = pvc + NBC;                  // NBF
  int* pic = (int*)(pvf + NBF);             // NBC
  int* pif = pic + NBC;                     // NBF

  hipLaunchKernelGGL(k_init,  dim3(5),   dim3(256), 0, stream, x, freqp, fws, dstt);
  hipLaunchKernelGGL(k_coarse, dim3(NCC), dim3(256), 0, stream, fws, part_c);
  hipLaunchKernelGGL(k_cfin,  dim3(NBC), dim3(256), 0, stream, fws, dstt, pvc, pic);
  hipLaunchKernelGGL(k_fine,  dim3(NFC), dim3(256), 0, stream, fws, pvc, pic, part_f);
  hipLaunchKernelGGL(k_ffin,  dim3(NBF), dim3(256), 0, stream, fws, dstt, pvf, pif);
  hipLaunchKernelGGL(k_out,   dim3(1),   dim3(256), 0, stream, pvc, pic, pvf, pif, out);
}

// Round 11
// 58.900 us; speedup vs baseline: 1.7600x; 1.1744x over previous
//
#include <hip/hip_runtime.h>

#define L    2048
#define HALF 1024
#define NM   10
#define NG   20
#define NF   30

#define NCC  4000   // coarse blocks = combos (m,i2,i3)
#define NFC  900    // fine blocks = combos (j2,j3)
#define NBC  313    // ceil(80000/256)  k_cfin blocks
#define NBF  106    // ceil(27000/256)  k_ffin blocks

// ---- float workspace layout (float indices) ----
#define OFF_SC   0                        // float2 sc[1024] = {sin^2, sin*td}
#define OFF_TAB  2048                     // float2 tab[NM*HALF] = {lc, ls}
#define OFF_G20  (2048 + 2*NM*HALF)       // 22528: grid20[20]
#define OFF_R20  (OFF_G20 + 20)           // -1/grid20 [20]
#define OFF_PC   (OFF_R20 + 20)           // float2 part_c[80000]  (160000 floats)
#define OFF_PF   (OFF_PC + 160000)        // float2 part_f[27000]  (54000 floats)
#define OFF_DWS  (OFF_PF + 54000)         // 236568 floats -> byte 946272 (%8==0)

#define EXP2F(x) __builtin_amdgcn_exp2f(x)
#define LOG2F(x) __builtin_amdgcn_logf(x)

__device__ __forceinline__ float grid20(int i) {
  double e = -1.0 + 2.0 * (double)i / 19.0;
  return (float)exp2(e * 3.3219280948873623478703194294894);
}
__device__ __forceinline__ float finev(float c, int j) {
  return (float)((double)c * 0.8 + (double)j * ((double)c * 0.4 / 29.0));
}
__device__ __forceinline__ double mse_from(double sgg2, double sgt, double sum_tt) {
  double S = sgg2; if (S < 0.0) S = 0.0;
  double d = sqrt(S / (double)(L - 1)) + 1e-6;
  return (S / (d * d) - 2.0 * sgt / d + sum_tt) / (double)L;
}
__device__ __forceinline__ void vt_wave_reduce(double& v, int& t) {
  for (int o = 32; o > 0; o >>= 1) {
    double ov = __shfl_down(v, o);
    int ot = __shfl_down(t, o);
    if (ov < v || (ov == v && ot < t)) { v = ov; t = ot; }
  }
}
__device__ __forceinline__ void vt_block_merge(double& v, int& t, double* sv, int* st) {
  int lane = threadIdx.x & 63, w = threadIdx.x >> 6;
  vt_wave_reduce(v, t);
  if (lane == 0) { sv[w] = v; st[w] = t; }
  __syncthreads();
  if (threadIdx.x == 0) {
    for (int k = 1; k < 4; k++)
      if (sv[k] < v || (sv[k] == v && st[k] < t)) { v = sv[k]; t = st[k]; }
  }
}

// ---------------- K1: setup (block 0) + tables (blocks 1..4, recurrence) ---
__global__ __launch_bounds__(256) void k_init(const float* __restrict__ x,
                                              const int* __restrict__ freqp,
                                              float* __restrict__ fws,
                                              double* __restrict__ dstt) {
  if (blockIdx.x == 0) {
    int tid = threadIdx.x;
    int lane = tid & 63, w = tid >> 6;
    __shared__ double sh[8];
    __shared__ double s_mean, s_d;

    double sx = 0.0, sxx = 0.0;
    for (int l = tid; l < L; l += 256) {
      double v = (double)x[l];
      sx += v; sxx += v * v;
    }
    for (int o = 32; o > 0; o >>= 1) { sx += __shfl_down(sx, o); sxx += __shfl_down(sxx, o); }
    if (lane == 0) { sh[w] = sx; sh[4 + w] = sxx; }
    __syncthreads();
    if (tid == 0) {
      sx = sh[0] + sh[1] + sh[2] + sh[3];
      sxx = sh[4] + sh[5] + sh[6] + sh[7];
      double mean = sx / (double)L;
      double S = sxx - sx * sx / (double)L; if (S < 0.0) S = 0.0;
      s_mean = mean; s_d = sqrt(S / (double)(L - 1)) + 1e-6;
    }
    __syncthreads();
    double mean = s_mean, d = s_d;
    double freq = (double)freqp[0];

    double stt = 0.0;
    for (int l = tid; l < HALF; l += 256) {
      float tva = (float)(((double)x[l] - mean) / d);
      float tvb = (float)(((double)x[L - 1 - l] - mean) / d);
      float tdv = tva - tvb;
      double t = -1.0 + 2.0 * (double)l / 2047.0;
      float spv = (float)sin(6.2831853071795864769 * freq * t);
      float2 scv; scv.x = spv * spv; scv.y = spv * tdv;
      reinterpret_cast<float2*>(fws + OFF_SC)[l] = scv;
      stt += (double)tva * (double)tva + (double)tvb * (double)tvb;
    }
    for (int o = 32; o > 0; o >>= 1) { stt += __shfl_down(stt, o); }
    __syncthreads();
    if (lane == 0) { sh[w] = stt; }
    __syncthreads();
    if (tid == 0) { dstt[0] = sh[0] + sh[1] + sh[2] + sh[3]; }
  } else {
    // blocks 1..4: one thread per l; sincos once, then 10 angle-addition steps
    int l = (blockIdx.x - 1) * 256 + threadIdx.x;   // [0, 1024)
    double freq = (double)freqp[0];
    double t = -1.0 + 2.0 * (double)l / 2047.0;
    double theta = 6.2831853071795864769 * freq * t * 0.25;   // phi/4
    double s1, c1;
    sincos(theta, &s1, &c1);
    double sk = s1, ck = c1;
    float2* tabp = reinterpret_cast<float2*>(fws + OFF_TAB);
#pragma unroll
    for (int m = 0; m < NM; ++m) {
      float2 v;
      v.x = fmaxf(LOG2F(fabsf((float)ck)), -1.0e4f);
      v.y = fmaxf(LOG2F(fabsf((float)sk)), -1.0e4f);
      tabp[m * HALF + l] = v;
      double sn = sk * c1 + ck * s1;
      double cn = ck * c1 - sk * s1;
      sk = sn; ck = cn;
    }
    if (blockIdx.x == 1 && threadIdx.x < NG) {
      float g = grid20(threadIdx.x);
      fws[OFF_G20 + threadIdx.x] = g;
      fws[OFF_R20 + threadIdx.x] = -1.0f / g;
    }
  }
}

// ---------------- K2: coarse scan — i1 pairs share each LDS read -----------
// block = combo (m,i2,i3); LDS float4 row {lsum, sx, sy, 0}; wave w owns
// i1 in [5w, 5w+5) processed as passes {0,1},{2,3},{4}; scalar accums only.
__global__ __launch_bounds__(256) void k_coarse(const float* __restrict__ fws,
                                                float2* __restrict__ part) {
  __shared__ float4 row[HALF];   // 16 KB
  int tid = threadIdx.x, lane = tid & 63, w = tid >> 6;
  int combo = blockIdx.x;
  int m = combo / (NG * NG);
  int i23 = combo % (NG * NG);
  float n2 = fws[OFF_G20 + i23 / NG];
  float n3 = fws[OFF_G20 + i23 % NG];

  const float2* tab = reinterpret_cast<const float2*>(fws + OFF_TAB) + m * HALF;
  const float2* sc = reinterpret_cast<const float2*>(fws + OFF_SC);
#pragma unroll
  for (int k = 0; k < 4; k++) {
    int l = tid + k * 256;
    float2 tb = tab[l];
    float2 s = sc[l];
    float4 v;
    v.x = LOG2F(EXP2F(n2 * tb.x) + EXP2F(n3 * tb.y));
    v.y = s.x; v.z = s.y; v.w = 0.0f;
    row[l] = v;
  }
  __syncthreads();

  int base = combo * 20;
#pragma unroll
  for (int pass = 0; pass < 3; ++pass) {
    const bool two = (pass < 2);
    int i1a = w * 5 + pass * 2;
    float r0 = fws[OFF_R20 + i1a];
    float r1 = two ? fws[OFF_R20 + i1a + 1] : 0.0f;
    float sgg0 = 0.0f, sgt0 = 0.0f, sgg1 = 0.0f, sgt1 = 0.0f;
#pragma unroll 4
    for (int it = 0; it < 16; ++it) {
      float4 v = row[lane + it * 64];
      float e0 = EXP2F(r0 * v.x);
      sgg0 = fmaf(e0 * e0, v.y, sgg0);
      sgt0 = fmaf(e0, v.z, sgt0);
      if (two) {
        float e1 = EXP2F(r1 * v.x);
        sgg1 = fmaf(e1 * e1, v.y, sgg1);
        sgt1 = fmaf(e1, v.z, sgt1);
      }
    }
    for (int o = 32; o > 0; o >>= 1) {
      sgg0 += __shfl_down(sgg0, o);
      sgt0 += __shfl_down(sgt0, o);
      if (two) {
        sgg1 += __shfl_down(sgg1, o);
        sgt1 += __shfl_down(sgt1, o);
      }
    }
    if (lane == 0) {
      part[base + i1a] = make_float2(sgg0, sgt0);
      if (two) part[base + i1a + 1] = make_float2(sgg1, sgt1);
    }
  }
}

// ---------------- K3: coarse finalize (f64 mse) + argmin stage 1 -----------
__global__ __launch_bounds__(256) void k_cfin(const float* __restrict__ fws,
                                              const double* __restrict__ dstt,
                                              double* __restrict__ pv,
                                              int* __restrict__ pi) {
  int t = blockIdx.x * 256 + threadIdx.x;
  double best = 1e300; int bi = 0x7fffffff;
  if (t < NM * NG * NG * NG) {
    int m = t / (NG * NG * NG);
    int i1 = (t / (NG * NG)) % NG;
    int i23 = t % (NG * NG);
    float2 p = reinterpret_cast<const float2*>(fws + OFF_PC)[(m * 400 + i23) * 20 + i1];
    best = mse_from(2.0 * (double)p.x, (double)p.y, dstt[0]);
    bi = t;
  }
  __shared__ double sv[4];
  __shared__ int st[4];
  vt_block_merge(best, bi, sv, st);
  if (threadIdx.x == 0) { pv[blockIdx.x] = best; pi[blockIdx.x] = bi; }
}

// ---------------- K4: fine scan (in-block coarse argmin stage 2) -----------
// block = fc (j2,j3); wave w owns j1 in [8w, 8w+cnt) as full pairs (4,4,4,3)
__global__ __launch_bounds__(256) void k_fine(const float* __restrict__ fws,
                                              const double* __restrict__ pvc,
                                              const int* __restrict__ pic,
                                              float2* __restrict__ partf) {
  __shared__ float4 row[HALF];
  __shared__ double sv[4];
  __shared__ int st[4];
  __shared__ float s_cn[4];
  {
    double v = 1e300; int t = 0x7fffffff;
    for (int i = threadIdx.x; i < NBC; i += 256) {
      double ov = pvc[i]; int ot = pic[i];
      if (ov < v || (ov == v && ot < t)) { v = ov; t = ot; }
    }
    vt_block_merge(v, t, sv, st);
    if (threadIdx.x == 0) {
      int ci = t;
      int m  = ci / (NG * NG * NG);
      int rr = ci % (NG * NG * NG);
      s_cn[0] = grid20(rr / (NG * NG));
      s_cn[1] = grid20((rr / NG) % NG);
      s_cn[2] = grid20(rr % NG);
      s_cn[3] = (float)m;
    }
  }
  __syncthreads();
  float cn1 = s_cn[0], cn2 = s_cn[1], cn3 = s_cn[2];
  int m = (int)s_cn[3];

  int tid = threadIdx.x, lane = tid & 63, w = tid >> 6;
  int fc = blockIdx.x;
  float n2 = finev(cn2, fc / NF), n3 = finev(cn3, fc % NF);

  const float2* tab = reinterpret_cast<const float2*>(fws + OFF_TAB) + m * HALF;
  const float2* sc = reinterpret_cast<const float2*>(fws + OFF_SC);
#pragma unroll
  for (int k = 0; k < 4; k++) {
    int l = tid + k * 256;
    float2 tb = tab[l];
    float2 s = sc[l];
    float4 v;
    v.x = LOG2F(EXP2F(n2 * tb.x) + EXP2F(n3 * tb.y));
    v.y = s.x; v.z = s.y; v.w = 0.0f;
    row[l] = v;
  }
  __syncthreads();

  int base = fc * 30;
  int npairs = (w < 3) ? 4 : 3;    // j1 counts 8,8,8,6 -> all full pairs
  for (int pp = 0; pp < npairs; ++pp) {
    int j1a = w * 8 + pp * 2;
    float r0 = -1.0f / finev(cn1, j1a);
    float r1 = -1.0f / finev(cn1, j1a + 1);
    float sgg0 = 0.0f, sgt0 = 0.0f, sgg1 = 0.0f, sgt1 = 0.0f;
#pragma unroll 4
    for (int it = 0; it < 16; ++it) {
      float4 v = row[lane + it * 64];
      float e0 = EXP2F(r0 * v.x);
      sgg0 = fmaf(e0 * e0, v.y, sgg0);
      sgt0 = fmaf(e0, v.z, sgt0);
      float e1 = EXP2F(r1 * v.x);
      sgg1 = fmaf(e1 * e1, v.y, sgg1);
      sgt1 = fmaf(e1, v.z, sgt1);
    }
    for (int o = 32; o > 0; o >>= 1) {
      sgg0 += __shfl_down(sgg0, o);
      sgt0 += __shfl_down(sgt0, o);
      sgg1 += __shfl_down(sgg1, o);
      sgt1 += __shfl_down(sgt1, o);
    }
    if (lane == 0) {
      partf[base + j1a]     = make_float2(sgg0, sgt0);
      partf[base + j1a + 1] = make_float2(sgg1, sgt1);
    }
  }
}

// ---------------- K5: fine finalize + argmin stage 1 -----------------------
__global__ __launch_bounds__(256) void k_ffin(const float* __restrict__ fws,
                                              const double* __restrict__ dstt,
                                              double* __restrict__ pv,
                                              int* __restrict__ pi) {
  int t = blockIdx.x * 256 + threadIdx.x;
  double best = 1e300; int bi = 0x7fffffff;
  if (t < NF * NF * NF) {
    int j1 = t / (NF * NF);
    int fc = t % (NF * NF);
    float2 p = reinterpret_cast<const float2*>(fws + OFF_PF)[fc * 30 + j1];
    best = mse_from(2.0 * (double)p.x, (double)p.y, dstt[0]);
    bi = t;
  }
  __shared__ double sv[4];
  __shared__ int st[4];
  vt_block_merge(best, bi, sv, st);
  if (threadIdx.x == 0) { pv[blockIdx.x] = best; pi[blockIdx.x] = bi; }
}

// ---------------- K6: final argmins + emit ---------------------------------
__global__ __launch_bounds__(256) void k_out(const double* __restrict__ pvc,
                                             const int* __restrict__ pic,
                                             const double* __restrict__ pvf,
                                             const int* __restrict__ pif,
                                             float* __restrict__ out) {
  __shared__ double sv[4];
  __shared__ int st[4];
  __shared__ int s_ci;
  {
    double v = 1e300; int t = 0x7fffffff;
    for (int i = threadIdx.x; i < NBC; i += 256) {
      double ov = pvc[i]; int ot = pic[i];
      if (ov < v || (ov == v && ot < t)) { v = ov; t = ot; }
    }
    vt_block_merge(v, t, sv, st);
    if (threadIdx.x == 0) s_ci = t;
  }
  __syncthreads();
  {
    double v = 1e300; int t = 0x7fffffff;
    for (int i = threadIdx.x; i < NBF; i += 256) {
      double ov = pvf[i]; int ot = pif[i];
      if (ov < v || (ov == v && ot < t)) { v = ov; t = ot; }
    }
    vt_block_merge(v, t, sv, st);
    if (threadIdx.x == 0) {
      int ci = s_ci;
      int m  = ci / (NG * NG * NG);
      int rr = ci % (NG * NG * NG);
      float cn1 = grid20(rr / (NG * NG));
      float cn2 = grid20((rr / NG) % NG);
      float cn3 = grid20(rr % NG);
      int fi = t;
      int f1 = fi / (NF * NF);
      int fc = fi % (NF * NF);
      out[0] = (float)(m + 1);
      out[1] = finev(cn1, f1);
      out[2] = finev(cn2, fc / NF);
      out[3] = finev(cn3, fc % NF);
    }
  }
}

extern "C" void kernel_launch(void* const* d_in, const int* in_sizes, int n_in,
                              void* d_out, int out_size, void* d_ws, size_t ws_size,
                              hipStream_t stream) {
  const float* x = (const float*)d_in[0];
  const int* freqp = (const int*)d_in[1];
  float* out = (float*)d_out;
  float* fws = (float*)d_ws;

  float2* part_c = reinterpret_cast<float2*>(fws + OFF_PC);
  float2* part_f = reinterpret_cast<float2*>(fws + OFF_PF);
  double* D0  = (double*)(fws + OFF_DWS);   // byte 946272, 8-aligned
  double* dstt = D0;                        // [1]
  double* pvc = D0 + 1;                     // NBC
  double* pvf = pvc + NBC;                  // NBF
  int* pic = (int*)(pvf + NBF);             // NBC
  int* pif = pic + NBC;                     // NBF

  hipLaunchKernelGGL(k_init,  dim3(5),   dim3(256), 0, stream, x, freqp, fws, dstt);
  hipLaunchKernelGGL(k_coarse, dim3(NCC), dim3(256), 0, stream, fws, part_c);
  hipLaunchKernelGGL(k_cfin,  dim3(NBC), dim3(256), 0, stream, fws, dstt, pvc, pic);
  hipLaunchKernelGGL(k_fine,  dim3(NFC), dim3(256), 0, stream, fws, pvc, pic, part_f);
  hipLaunchKernelGGL(k_ffin,  dim3(NBF), dim3(256), 0, stream, fws, dstt, pvf, pif);
  hipLaunchKernelGGL(k_out,   dim3(1),   dim3(256), 0, stream, pvc, pic, pvf, pif, out);
}